// Round 11
// baseline (1035.515 us; speedup 1.0000x reference)
//
#include <hip/hip_runtime.h>
#include <math.h>

#define KSIZE 7
#define C_CH  256
#define HW    256
#define BATCH 8

#define RPW   32            // output rows per wave (vert. redundancy 38/32)

// ---------------------------------------------------------------------------
// Kernel 1: synthesize the 256 x 7 x 7 Gabor filter bank into d_ws.
// ---------------------------------------------------------------------------
__global__ void gabor_weights_kernel(const float* __restrict__ log_sigma,
                                     const float* __restrict__ log_freq,
                                     const float* __restrict__ theta,
                                     float* __restrict__ gw) {
    int c = threadIdx.x;
    if (c >= C_CH) return;
    float sigma = expf(log_sigma[c]);
    float freq  = expf(log_freq[c]);
    float ct = cosf(theta[c]);
    float st = sinf(theta[c]);
    float inv_sigma = 1.0f / sigma;
    float vals[KSIZE * KSIZE];
    float sum = 0.0f;
    #pragma unroll
    for (int i = 0; i < KSIZE; ++i) {
        #pragma unroll
        for (int j = 0; j < KSIZE; ++j) {
            float dx = (float)(i - 3);
            float dy = (float)(j - 3);
            float x0 = (dx * ct + dy * st) * inv_sigma;
            float x1 = (-dx * st + dy * ct) * inv_sigma;
            float g  = expf(-0.5f * (x0 * x0 + x1 * x1));
            float v  = g * cosf(6.283185307179586f * freq * x0);
            vals[i * KSIZE + j] = v;
            sum += v;
        }
    }
    float inv = 1.0f / sum;
    #pragma unroll
    for (int k = 0; k < KSIZE * KSIZE; ++k)
        gw[c * (KSIZE * KSIZE) + k] = vals[k] * inv;
}

// ---------------------------------------------------------------------------
// Kernel 2: depthwise 7x7 conv -- NO LDS STAGING, NO BARRIERS.
// Each lane owns 4 output cols (col0=4*lane); a wave sweeps RPW=32 rows.
// Per input row: ONE float4 load (lane's own cols -- zero horizontal
// redundancy); the 3-left/3-right halo floats come from neighbor lanes via
// __shfl_up/down (ds_bpermute: conflict-free, no LDS alloc, no sync).
// A 7-row x 10-float register window rolls down the image (full unroll ->
// static indices, no scratch).  Vertical redundancy 38/32 = 1.19x; the
// wave-adjacent halo re-reads hit L2.  Pure TLP latency hiding: no wait
// can couple waves; stores are fire-and-forget through L2.
// ---------------------------------------------------------------------------
__device__ __forceinline__ void mkf(const float4 M, const int lane, float* fr) {
    // left halo: cols 4l-3..4l-1 = lane l-1's M.y/z/w
    float a = __shfl_up(M.y, 1);
    float b = __shfl_up(M.z, 1);
    float d = __shfl_up(M.w, 1);
    // right halo: cols 4l+4..4l+6 = lane l+1's M.x/y/z
    float e = __shfl_down(M.x, 1);
    float g = __shfl_down(M.y, 1);
    float h = __shfl_down(M.z, 1);
    const bool L = (lane == 0), R = (lane == 63);
    fr[0] = L ? 0.f : a;
    fr[1] = L ? 0.f : b;
    fr[2] = L ? 0.f : d;
    fr[3] = M.x; fr[4] = M.y; fr[5] = M.z; fr[6] = M.w;
    fr[7] = R ? 0.f : e;
    fr[8] = R ? 0.f : g;
    fr[9] = R ? 0.f : h;
}

__global__ __launch_bounds__(256, 4)
void gabor_conv_kernel(const float* __restrict__ x,
                       const float* __restrict__ gw,
                       float* __restrict__ out) {
    const int tid  = threadIdx.x;
    const int lane = tid & 63;
    const int wv   = tid >> 6;
    const int c    = blockIdx.y;
    const int n    = blockIdx.z;
    const int row0 = (blockIdx.x * 4 + wv) * RPW;   // first output row

    const size_t plane = ((size_t)n * C_CH + c) * (size_t)(HW * HW);
    const float* xp = x + plane;
    float*       op = out + plane;
    const int col0 = lane * 4;

    // ---- weights: block-uniform loads -> scalar regs
    float w[KSIZE * KSIZE];
    const float* wp = gw + c * (KSIZE * KSIZE);
    #pragma unroll
    for (int k = 0; k < KSIZE * KSIZE; ++k) w[k] = wp[k];

    // row loader: wave-uniform bounds branch, zero outside image
    auto ldM = [&](int ri) -> float4 {
        if (ri >= 0 && ri < HW)
            return *reinterpret_cast<const float4*>(xp + (size_t)ri * HW + col0);
        return make_float4(0.f, 0.f, 0.f, 0.f);
    };

    // ---- preload window: input rows row0-3 .. row0+2 -> slots 0..5
    float f[7][10];
    {
        float4 m[6];
        #pragma unroll
        for (int k = 0; k < 6; ++k) m[k] = ldM(row0 - 3 + k);
        #pragma unroll
        for (int k = 0; k < 6; ++k) mkf(m[k], lane, f[k]);
    }
    // ---- 2-deep prefetch pipeline
    float4 pf0 = ldM(row0 + 3);
    float4 pf1 = ldM(row0 + 4);

    #pragma unroll
    for (int r = 0; r < RPW; ++r) {
        float4 nxt = ldM(row0 + r + 5);          // prefetch 2 ahead
        mkf(pf0, lane, f[(r + 6) % 7]);          // row row0+r+3 -> slot
        pf0 = pf1; pf1 = nxt;                    // renamed by unroll

        float acc[4] = {0.f, 0.f, 0.f, 0.f};
        #pragma unroll
        for (int ki = 0; ki < KSIZE; ++ki) {
            const float* fr = f[(r + ki) % 7];   // static after unroll
            #pragma unroll
            for (int cc = 0; cc < 4; ++cc) {
                #pragma unroll
                for (int j = 0; j < KSIZE; ++j)
                    acc[cc] += fr[cc + j] * w[ki * KSIZE + j];
            }
        }

        float4 v = make_float4(acc[0], acc[1], acc[2], acc[3]);
        *reinterpret_cast<float4*>(op + (size_t)(row0 + r) * HW + col0) = v;
    }
}

extern "C" void kernel_launch(void* const* d_in, const int* in_sizes, int n_in,
                              void* d_out, int out_size, void* d_ws, size_t ws_size,
                              hipStream_t stream) {
    const float* x  = (const float*)d_in[0];
    const float* ls = (const float*)d_in[1];
    const float* lf = (const float*)d_in[2];
    const float* th = (const float*)d_in[3];
    float* out = (float*)d_out;
    float* gw  = (float*)d_ws;   // 256*49*4 = 50176 bytes of scratch

    gabor_weights_kernel<<<1, 256, 0, stream>>>(ls, lf, th, gw);

    dim3 grid(HW / (4 * RPW), C_CH, BATCH);   // (2, 256, 8)
    gabor_conv_kernel<<<grid, 256, 0, stream>>>(x, gw, out);
}